// Round 6
// baseline (406.139 us; speedup 1.0000x reference)
//
#include <hip/hip_runtime.h>

// HeteroSAGE on MI355X — round 6: agg VALU diet (1-op unpacks, 32-bit addr),
// memset + merged setup||count dispatch.
//
// Pipeline (memset + 6 dispatches):
//   0. memsetAsync: cnt (4N ints) + desc (257 u64) -> 0
//   1. setupcount: [blocks 0..3124] x->bf16, fold weights, build Wz bf16;
//      [blocks 3125..] per-relation in-degree atomics + per-edge rank
//   2. scan: single-kernel decoupled-lookback exclusive prefix
//   3. fill (y=4): col[rowptr[d]+rank[e]] = src (no atomics)
//   4. agg (y=4): per-(node,rel) mean, quarter-wave, 8-edge unroll -> aggb bf16
//   5. gemm0z (y=2): LDS-staged A (3 segs), 16-MFMA k-iters; h->LDS bf16;
//      z via 8 MFMA vs zero-padded Wz; direct stores
//   6. l1_agg (y=2): 8 lanes/node CSR walk, xor-reduce, out += mean(z)

#define DIN 128
#define DH  256
#define LDSA 136    // A-tile row stride (shorts): 128+8 pad
#define LDSH 264    // h-tile row stride (shorts): 256+8 pad

typedef __attribute__((ext_vector_type(8))) short bf16x8;
typedef __attribute__((ext_vector_type(4))) float f32x4;

__device__ __forceinline__ float blo(unsigned u) {           // even element
    return __uint_as_float(u << 16);
}
__device__ __forceinline__ float bhi(unsigned u) {           // odd element
    return __uint_as_float(u & 0xffff0000u);
}
__device__ __forceinline__ unsigned short f2bf(float f) {
    unsigned int u = __float_as_uint(f);
    u = (u + 0x7fffu + ((u >> 16) & 1u)) >> 16;   // RNE
    return (unsigned short)u;
}

// ---------------- setup || count ----------------
__global__ __launch_bounds__(256) void setupcount_kernel(
    const float* __restrict__ x_tx, const float* __restrict__ x_addr,
    const int* __restrict__ e0, const int* __restrict__ e1,
    const int* __restrict__ e2, const int* __restrict__ e3,
    const float* __restrict__ Wl0_tt, const float* __restrict__ Wl0_aa,
    const float* __restrict__ Wl0_at, const float* __restrict__ Wl0_ta,
    const float* __restrict__ Wr0_tt, const float* __restrict__ Wr0_aa,
    const float* __restrict__ Wr0_at, const float* __restrict__ Wr0_ta,
    const float* __restrict__ bl0_tt, const float* __restrict__ bl0_aa,
    const float* __restrict__ bl0_at, const float* __restrict__ bl0_ta,
    const float* __restrict__ Wl1_tt, const float* __restrict__ Wl1_aa,
    const float* __restrict__ Wl1_at, const float* __restrict__ Wl1_ta,
    const float* __restrict__ Wr1_tt, const float* __restrict__ Wr1_aa,
    const float* __restrict__ Wr1_at, const float* __restrict__ Wr1_ta,
    const float* __restrict__ bl1_tt, const float* __restrict__ bl1_aa,
    const float* __restrict__ bl1_at, const float* __restrict__ bl1_ta,
    unsigned short* __restrict__ xb_tx, unsigned short* __restrict__ xb_ad,
    int* __restrict__ cnt, int* __restrict__ rank,
    unsigned short* __restrict__ wb_tt, unsigned short* __restrict__ wb_aa,
    unsigned short* __restrict__ wb_at, unsigned short* __restrict__ wb_ta,
    unsigned short* __restrict__ wr0c_tx, unsigned short* __restrict__ wr0c_ad,
    float* __restrict__ b0c, unsigned short* __restrict__ wzb,
    float* __restrict__ b1c, int N, int E, int nconvB, int countB)
{
    const int bid = blockIdx.x;
    if (bid >= nconvB) {
        // ---- count path ----
        int cb = bid - nconvB;
        int r = cb / countB;
        int i = (cb % countB) * 256 + threadIdx.x;
        const int* e = (r == 0) ? e0 : (r == 1) ? e1 : (r == 2) ? e2 : e3;
        if (i < E) {
            int d = e[E + i];
            rank[(size_t)r * E + i] = atomicAdd(&cnt[r * N + d], 1);
        }
        return;
    }
    // ---- setup path ----
    int i = bid * 256 + threadIdx.x;
    int nconv = N * DIN / 8;                 // 800000
    if (i < nconv) {
        {
            const float4* p = (const float4*)(x_tx + (size_t)i * 8);
            float4 a = p[0], b = p[1];
            uint4 o;
            o.x = (unsigned)f2bf(a.x) | ((unsigned)f2bf(a.y) << 16);
            o.y = (unsigned)f2bf(a.z) | ((unsigned)f2bf(a.w) << 16);
            o.z = (unsigned)f2bf(b.x) | ((unsigned)f2bf(b.y) << 16);
            o.w = (unsigned)f2bf(b.z) | ((unsigned)f2bf(b.w) << 16);
            *(uint4*)(xb_tx + (size_t)i * 8) = o;
        }
        {
            const float4* p = (const float4*)(x_addr + (size_t)i * 8);
            float4 a = p[0], b = p[1];
            uint4 o;
            o.x = (unsigned)f2bf(a.x) | ((unsigned)f2bf(a.y) << 16);
            o.y = (unsigned)f2bf(a.z) | ((unsigned)f2bf(a.w) << 16);
            o.z = (unsigned)f2bf(b.x) | ((unsigned)f2bf(b.y) << 16);
            o.w = (unsigned)f2bf(b.z) | ((unsigned)f2bf(b.w) << 16);
            *(uint4*)(xb_ad + (size_t)i * 8) = o;
        }
    }
    if (i < DH * DIN) {
        wb_tt[i] = f2bf(Wl0_tt[i]);
        wb_aa[i] = f2bf(Wl0_aa[i]);
        wb_at[i] = f2bf(Wl0_at[i]);
        wb_ta[i] = f2bf(Wl0_ta[i]);
        wr0c_tx[i] = f2bf(Wr0_tt[i] + Wr0_at[i]);
        wr0c_ad[i] = f2bf(Wr0_aa[i] + Wr0_ta[i]);
    }
    if (i < DH) {
        b0c[i]      = bl0_tt[i] + bl0_at[i];
        b0c[DH + i] = bl0_aa[i] + bl0_ta[i];
    }
    if (i < 2 * 16 * DH) {                    // wzb: [type][16][256] bf16, rows>=6 zero
        int type = i >> 12;
        int rem = i & 4095;
        int r = rem >> 8;
        int c = rem & 255;
        float v = 0.f;
        if (r < 6) {
            const float* A = type ? Wl1_aa : Wl1_tt;
            const float* B = type ? Wl1_at : Wl1_ta;
            if (r == 0) v = A[c];
            else if (r == 1) v = A[DH + c];
            else if (r == 2) v = B[c];
            else if (r == 3) v = B[DH + c];
            else if (r == 4) v = type ? (Wr1_aa[c] + Wr1_ta[c]) : (Wr1_tt[c] + Wr1_at[c]);
            else             v = type ? (Wr1_aa[DH + c] + Wr1_ta[DH + c])
                                      : (Wr1_tt[DH + c] + Wr1_at[DH + c]);
        }
        wzb[i] = f2bf(v);
    }
    if (i < 2) {
        b1c[i]     = bl1_tt[i] + bl1_at[i];
        b1c[2 + i] = bl1_aa[i] + bl1_ta[i];
    }
}

// single-kernel decoupled-lookback exclusive scan (ticket-ordered)
__global__ __launch_bounds__(1024) void scan_kernel(
    const int* __restrict__ cnt, int* __restrict__ excl,
    unsigned long long* __restrict__ desc, int n)
{
    __shared__ int sdata[1024];
    __shared__ int sseg;
    __shared__ int sprev;
    if (threadIdx.x == 0) sseg = (int)atomicAdd(&desc[256], 1ULL);
    __syncthreads();
    int seg = sseg;
    int i = seg * 1024 + threadIdx.x;
    int v = (i < n) ? cnt[i] : 0;
    sdata[threadIdx.x] = v;
    __syncthreads();
    for (int off = 1; off < 1024; off <<= 1) {
        int t = (threadIdx.x >= off) ? sdata[threadIdx.x - off] : 0;
        __syncthreads();
        sdata[threadIdx.x] += t;
        __syncthreads();
    }
    if (threadIdx.x == 0) {
        int total = sdata[1023];
        int prev = 0;
        if (seg == 0) {
            atomicExch(&desc[0], ((unsigned long long)(unsigned)total << 2) | 2ULL);
        } else {
            atomicExch(&desc[seg], ((unsigned long long)(unsigned)total << 2) | 1ULL);
            int j = seg - 1;
            for (;;) {
                unsigned long long d = atomicAdd(&desc[j], 0ULL);
                unsigned st = (unsigned)(d & 3ULL);
                if (st == 0u) continue;
                prev += (int)(d >> 2);
                if (st == 2u) break;
                --j;
            }
            atomicExch(&desc[seg],
                       ((unsigned long long)(unsigned)(prev + total) << 2) | 2ULL);
        }
        sprev = prev;
    }
    __syncthreads();
    if (i < n) excl[i] = sprev + sdata[threadIdx.x] - v;
}

__global__ __launch_bounds__(256) void fill_kernel(
    const int* __restrict__ e0, const int* __restrict__ e1,
    const int* __restrict__ e2, const int* __restrict__ e3,
    const int* __restrict__ rowptr, const int* __restrict__ rank,
    int* __restrict__ col, int E, int N)
{
    int r = blockIdx.y;
    const int* e = (r == 0) ? e0 : (r == 1) ? e1 : (r == 2) ? e2 : e3;
    int i = blockIdx.x * blockDim.x + threadIdx.x;
    if (i < E) {
        int s = e[i];
        int d = e[E + i];
        col[rowptr[r * N + d] + rank[(size_t)r * E + i]] = s;
    }
}

// ---------------- layer-0 mean aggregation: cheap unpack, 32-bit addr ----------
__global__ __launch_bounds__(256) void agg_kernel(
    const unsigned short* __restrict__ xb_tx, const unsigned short* __restrict__ xb_ad,
    const int* __restrict__ rowptr, const int* __restrict__ cnt,
    const int* __restrict__ col, unsigned short* __restrict__ aggb, int N)
{
    int r = blockIdx.y;                        // 0=tt 1=aa 2=at 3=ta
    const uint4* xs = (const uint4*)((r == 0 || r == 3) ? xb_tx : xb_ad);
    int wave = threadIdx.x >> 6;
    int l    = threadIdx.x & 63;
    int node = blockIdx.x * 4 + wave;
    if (node >= N) return;
    int base = rowptr[r * N + node];
    int c    = cnt[r * N + node];
    const int* cl = col + base;
    int q = l >> 4;
    int d = l & 15;
    // even-idx elements in aE[], odd-idx in aO[] (+ second chain bE/bO)
    float aE[4] = {}, aO[4] = {}, bE[4] = {}, bO[4] = {};
    int e0 = 0;
    for (; e0 + 8 <= c; e0 += 8) {
        unsigned iA = ((unsigned)cl[e0 + q] << 4) + d;
        unsigned iB = ((unsigned)cl[e0 + 4 + q] << 4) + d;
        uint4 uA = xs[iA];
        uint4 uB = xs[iB];
        aE[0] += blo(uA.x); aO[0] += bhi(uA.x);
        aE[1] += blo(uA.y); aO[1] += bhi(uA.y);
        aE[2] += blo(uA.z); aO[2] += bhi(uA.z);
        aE[3] += blo(uA.w); aO[3] += bhi(uA.w);
        bE[0] += blo(uB.x); bO[0] += bhi(uB.x);
        bE[1] += blo(uB.y); bO[1] += bhi(uB.y);
        bE[2] += blo(uB.z); bO[2] += bhi(uB.z);
        bE[3] += blo(uB.w); bO[3] += bhi(uB.w);
    }
    for (; e0 < c; e0 += 4) {
        int e = e0 + q;
        if (e < c) {
            unsigned iA = ((unsigned)cl[e] << 4) + d;
            uint4 u = xs[iA];
            aE[0] += blo(u.x); aO[0] += bhi(u.x);
            aE[1] += blo(u.y); aO[1] += bhi(u.y);
            aE[2] += blo(u.z); aO[2] += bhi(u.z);
            aE[3] += blo(u.w); aO[3] += bhi(u.w);
        }
    }
#pragma unroll
    for (int j = 0; j < 4; ++j) {
        aE[j] += bE[j];
        aO[j] += bO[j];
        aE[j] += __shfl_xor(aE[j], 16, 64);
        aE[j] += __shfl_xor(aE[j], 32, 64);
        aO[j] += __shfl_xor(aO[j], 16, 64);
        aO[j] += __shfl_xor(aO[j], 32, 64);
    }
    if (q == 0) {
        float sc = 1.0f / fmaxf((float)c, 1.0f);
        uint4 o;
        o.x = (unsigned)f2bf(aE[0] * sc) | ((unsigned)f2bf(aO[0] * sc) << 16);
        o.y = (unsigned)f2bf(aE[1] * sc) | ((unsigned)f2bf(aO[1] * sc) << 16);
        o.z = (unsigned)f2bf(aE[2] * sc) | ((unsigned)f2bf(aO[2] * sc) << 16);
        o.w = (unsigned)f2bf(aE[3] * sc) | ((unsigned)f2bf(aO[3] * sc) << 16);
        *(uint4*)(aggb + ((size_t)r * N + node) * DIN + d * 8) = o;
    }
}

// ---------------- gemm0 + fused layer-1 transform, LDS-staged A ----------------
__global__ __launch_bounds__(256) void gemm0z_kernel(
    const unsigned short* __restrict__ xb_tx, const unsigned short* __restrict__ xb_ad,
    const unsigned short* __restrict__ aggb,
    const unsigned short* __restrict__ wb_tt, const unsigned short* __restrict__ wb_at,
    const unsigned short* __restrict__ wr0c_tx,
    const unsigned short* __restrict__ wb_aa, const unsigned short* __restrict__ wb_ta,
    const unsigned short* __restrict__ wr0c_ad,
    const float* __restrict__ b0c, const unsigned short* __restrict__ wzb,
    const float* __restrict__ b1c,
    float* __restrict__ z, float* __restrict__ outp, int N)
{
    __shared__ unsigned short lds[3 * 64 * LDSA];   // 52224 B; h (64*LDSH) aliases it
    const int type = blockIdx.y;
    const unsigned short* xself = type ? xb_ad : xb_tx;
    const unsigned short* A0 = aggb + (size_t)(type ? 1 : 0) * N * DIN;  // aa / tt
    const unsigned short* A1 = aggb + (size_t)(type ? 3 : 2) * N * DIN;  // ta / at
    const unsigned short* W0 = type ? wb_aa   : wb_tt;
    const unsigned short* W1 = type ? wb_ta   : wb_at;
    const unsigned short* W2 = type ? wr0c_ad : wr0c_tx;
    const float* bias = b0c + type * DH;
    float* zA = type ? (z + (size_t)1 * N * 2) : z;                       // aa / tt
    float* zB = type ? (z + (size_t)2 * N * 2) : (z + (size_t)3 * N * 2); // at / ta
    float* outSelf = outp + (size_t)type * N * 2;

    const int t  = threadIdx.x;
    const int wv = t >> 6;
    const int l  = t & 63;
    const int q  = l >> 4;
    const int lr = l & 15;
    const int m0 = blockIdx.x * 64;
    const int n0 = wv * 64;

    // ---- phase 1: stage A tiles (3072 chunks of 16B; 12 per thread) ----
    {
        const uint4* As[3] = {(const uint4*)A0, (const uint4*)A1, (const uint4*)xself};
#pragma unroll
        for (int i = 0; i < 12; ++i) {
            int cid = i * 256 + t;
            int seg = cid >> 10;
            int rem = cid & 1023;
            int row = rem >> 4;
            int ch  = rem & 15;
            int gr = m0 + row; if (gr >= N) gr = N - 1;
            uint4 v = As[seg][((unsigned)gr << 4) + ch];
            *(uint4*)&lds[(seg * 64 + row) * LDSA + ch * 8] = v;
        }
    }
    __syncthreads();

    // ---- phase 2: K-loop ----
    f32x4 accm[4][4] = {};
    {
        const unsigned short* Ws[3] = {W0, W1, W2};
        for (int seg = 0; seg < 3; ++seg) {
            const unsigned short* W = Ws[seg];
            const unsigned short* la = &lds[(seg * 64 + lr) * LDSA + q * 8];
            const unsigned short* pb0 = W + (unsigned)(n0 + lr) * DIN + q * 8;
            const unsigned short* pb1 = W + (unsigned)(n0 + 16 + lr) * DIN + q * 8;
            const unsigned short* pb2 = W + (unsigned)(n0 + 32 + lr) * DIN + q * 8;
            const unsigned short* pb3 = W + (unsigned)(n0 + 48 + lr) * DIN + q * 8;
#pragma unroll
            for (int k = 0; k < DIN; k += 32) {
                bf16x8 b0 = *(const bf16x8*)(pb0 + k);
                bf16x8 b1 = *(const bf16x8*)(pb1 + k);
                bf16x8 b2 = *(const bf16x8*)(pb2 + k);
                bf16x8 b3 = *(const bf16x8*)(pb3 + k);
#pragma unroll
                for (int mt = 0; mt < 4; ++mt) {
                    bf16x8 a = *(const bf16x8*)(la + mt * 16 * LDSA + k);
                    accm[mt][0] = __builtin_amdgcn_mfma_f32_16x16x32_bf16(a, b0, accm[mt][0], 0, 0, 0);
                    accm[mt][1] = __builtin_amdgcn_mfma_f32_16x16x32_bf16(a, b1, accm[mt][1], 0, 0, 0);
                    accm[mt][2] = __builtin_amdgcn_mfma_f32_16x16x32_bf16(a, b2, accm[mt][2], 0, 0, 0);
                    accm[mt][3] = __builtin_amdgcn_mfma_f32_16x16x32_bf16(a, b3, accm[mt][3], 0, 0, 0);
                }
            }
        }
    }
    __syncthreads();   // all LDS-A reads done before h overwrites

    // ---- phase 3: h = relu(acc + bias) -> LDS bf16 ----
    {
        float bias_nt[4];
#pragma unroll
        for (int nt = 0; nt < 4; ++nt) bias_nt[nt] = bias[n0 + nt * 16 + lr];
#pragma unroll
        for (int mt = 0; mt < 4; ++mt) {
#pragma unroll
            for (int nt = 0; nt < 4; ++nt) {
                int colc = n0 + nt * 16 + lr;
#pragma unroll
                for (int rr = 0; rr < 4; ++rr) {
                    int row = mt * 16 + q * 4 + rr;
                    lds[row * LDSH + colc] =
                        f2bf(fmaxf(accm[mt][nt][rr] + bias_nt[nt], 0.f));
                }
            }
        }
    }
    __syncthreads();

    // ---- phase 4: z = h @ Wz^T (one 16-row m-tile per wave) ----
    {
        const unsigned short* wz = wzb + (size_t)type * 16 * DH;
        f32x4 az = {};
        const unsigned short* la = &lds[(wv * 16 + lr) * LDSH + q * 8];
        const unsigned short* pb = wz + lr * DH + q * 8;
#pragma unroll
        for (int k = 0; k < DH; k += 32) {
            bf16x8 a = *(const bf16x8*)(la + k);
            bf16x8 b = *(const bf16x8*)(pb + k);
            az = __builtin_amdgcn_mfma_f32_16x16x32_bf16(a, b, az, 0, 0, 0);
        }
        if (lr < 6) {
#pragma unroll
            for (int reg = 0; reg < 4; ++reg) {
                int node = m0 + wv * 16 + q * 4 + reg;
                if (node < N) {
                    float v = az[reg];
                    if (lr < 2)      zA[node * 2 + lr] = v;
                    else if (lr < 4) zB[node * 2 + lr - 2] = v;
                    else             outSelf[node * 2 + lr - 4] = v + b1c[type * 2 + lr - 4];
                }
            }
        }
    }
}

// ---------------- layer-1 aggregate (y=2): 8 lanes per node ----------------
__global__ __launch_bounds__(256) void l1_agg_kernel(
    const int* __restrict__ rowptr, const int* __restrict__ cnt, const int* __restrict__ col,
    const float* __restrict__ z, float* __restrict__ out, int N)
{
    const int type = blockIdx.y;
    const int rA = type ? 1 : 0;
    const int rB = type ? 3 : 2;
    const float* zAp = type ? (z + (size_t)1 * N * 2) : z;
    const float* zBp = type ? (z + (size_t)3 * N * 2) : (z + (size_t)2 * N * 2);
    float* outp = out + (size_t)type * N * 2;

    const int t = threadIdx.x;
    const int wave = t >> 6;
    const int l = t & 63;
    const int sub = l >> 3;       // node within wave's 8
    const int es  = l & 7;        // edge slot
    int node = blockIdx.x * 32 + wave * 8 + sub;
    bool valid = node < N;

    float ax = 0.f, ay = 0.f;
#pragma unroll
    for (int ri = 0; ri < 2; ++ri) {
        int rel = ri ? rB : rA;
        const float* zp = ri ? zBp : zAp;
        int b = 0, c = 0;
        if (valid) { b = rowptr[rel * N + node]; c = cnt[rel * N + node]; }
        const int* cl = col + b;
        float sx = 0.f, sy = 0.f;
        for (int e = es; e < c; e += 8) {
            int s = cl[e];
            float2 v = *(const float2*)(zp + (size_t)s * 2);
            sx += v.x; sy += v.y;
        }
        sx += __shfl_xor(sx, 1, 64); sy += __shfl_xor(sy, 1, 64);
        sx += __shfl_xor(sx, 2, 64); sy += __shfl_xor(sy, 2, 64);
        sx += __shfl_xor(sx, 4, 64); sy += __shfl_xor(sy, 4, 64);
        float sc = 1.0f / fmaxf((float)c, 1.0f);
        ax += sx * sc; ay += sy * sc;
    }
    if (valid && es == 0) {
        float2 o = *(float2*)(outp + (size_t)node * 2);   // self term from gemm0z
        o.x += ax; o.y += ay;
        *(float2*)(outp + (size_t)node * 2) = o;
    }
}

// ---------------- launch ----------------
extern "C" void kernel_launch(void* const* d_in, const int* in_sizes, int n_in,
                              void* d_out, int out_size, void* d_ws, size_t ws_size,
                              hipStream_t stream)
{
    const float* x_tx   = (const float*)d_in[0];
    const float* x_addr = (const float*)d_in[1];
    const int* e_tt = (const int*)d_in[2];
    const int* e_aa = (const int*)d_in[3];
    const int* e_at = (const int*)d_in[4];
    const int* e_ta = (const int*)d_in[5];
    const float* Wl0_tt = (const float*)d_in[6];
    const float* bl0_tt = (const float*)d_in[7];
    const float* Wr0_tt = (const float*)d_in[8];
    const float* Wl0_aa = (const float*)d_in[9];
    const float* bl0_aa = (const float*)d_in[10];
    const float* Wr0_aa = (const float*)d_in[11];
    const float* Wl0_at = (const float*)d_in[12];
    const float* bl0_at = (const float*)d_in[13];
    const float* Wr0_at = (const float*)d_in[14];
    const float* Wl0_ta = (const float*)d_in[15];
    const float* bl0_ta = (const float*)d_in[16];
    const float* Wr0_ta = (const float*)d_in[17];
    const float* Wl1_tt = (const float*)d_in[18];
    const float* bl1_tt = (const float*)d_in[19];
    const float* Wr1_tt = (const float*)d_in[20];
    const float* Wl1_aa = (const float*)d_in[21];
    const float* bl1_aa = (const float*)d_in[22];
    const float* Wr1_aa = (const float*)d_in[23];
    const float* Wl1_at = (const float*)d_in[24];
    const float* bl1_at = (const float*)d_in[25];
    const float* Wr1_at = (const float*)d_in[26];
    const float* Wl1_ta = (const float*)d_in[27];
    const float* bl1_ta = (const float*)d_in[28];
    const float* Wr1_ta = (const float*)d_in[29];

    const int N = in_sizes[0] / DIN;   // 50000
    const int E = in_sizes[2] / 2;     // 400000

    size_t off = 0;
    char* base = (char*)d_ws;
    auto alloc = [&](size_t bytes) -> void* {
        void* p = base + off;
        off += (bytes + 255) & ~(size_t)255;
        return p;
    };
    int*   cnt    = (int*)  alloc((size_t)4 * N * 4);        // zeroed by memset
    unsigned long long* desc = (unsigned long long*)alloc(257 * 8);  // contiguous w/ cnt
    int*   rowptr = (int*)  alloc((size_t)4 * N * 4);
    int*   rank   = (int*)  alloc((size_t)4 * E * 4);
    int*   col    = (int*)  alloc((size_t)4 * E * 4);
    unsigned short* xb_tx = (unsigned short*)alloc((size_t)N * DIN * 2);
    unsigned short* xb_ad = (unsigned short*)alloc((size_t)N * DIN * 2);
    unsigned short* aggb  = (unsigned short*)alloc((size_t)4 * N * DIN * 2);
    float* z      = (float*)alloc((size_t)4 * N * 2 * 4);
    unsigned short* wb_tt  = (unsigned short*)alloc((size_t)DH * DIN * 2);
    unsigned short* wb_aa  = (unsigned short*)alloc((size_t)DH * DIN * 2);
    unsigned short* wb_at  = (unsigned short*)alloc((size_t)DH * DIN * 2);
    unsigned short* wb_ta  = (unsigned short*)alloc((size_t)DH * DIN * 2);
    unsigned short* wr0c_tx = (unsigned short*)alloc((size_t)DH * DIN * 2);
    unsigned short* wr0c_ad = (unsigned short*)alloc((size_t)DH * DIN * 2);
    float* b0c    = (float*)alloc((size_t)2 * DH * 4);
    unsigned short* wzb = (unsigned short*)alloc((size_t)2 * 16 * DH * 2);
    float* b1c    = (float*)alloc((size_t)2 * 2 * 4);
    (void)ws_size;

    float* outp = (float*)d_out;
    const int n4 = 4 * N;

    // 0. zero cnt + desc (contiguous in ws)
    hipMemsetAsync(cnt, 0, ((size_t)4 * N * 4 + 255 & ~(size_t)255) + 257 * 8, stream);

    // 1. setup || count
    {
        int nconv = N * DIN / 8;                 // 800000
        int nconvB = (nconv + 255) / 256;        // 3125
        int countB = (E + 255) / 256;            // 1563
        setupcount_kernel<<<nconvB + 4 * countB, 256, 0, stream>>>(
            x_tx, x_addr, e_tt, e_aa, e_at, e_ta,
            Wl0_tt, Wl0_aa, Wl0_at, Wl0_ta,
            Wr0_tt, Wr0_aa, Wr0_at, Wr0_ta,
            bl0_tt, bl0_aa, bl0_at, bl0_ta,
            Wl1_tt, Wl1_aa, Wl1_at, Wl1_ta,
            Wr1_tt, Wr1_aa, Wr1_at, Wr1_ta,
            bl1_tt, bl1_aa, bl1_at, bl1_ta,
            xb_tx, xb_ad, cnt, rank,
            wb_tt, wb_aa, wb_at, wb_ta, wr0c_tx, wr0c_ad,
            b0c, wzb, b1c, N, E, nconvB, countB);
    }
    // 2. scan
    {
        int nb = (n4 + 1023) / 1024;
        scan_kernel<<<nb, 1024, 0, stream>>>(cnt, rowptr, desc, n4);
    }
    // 3. fill (no atomics)
    {
        dim3 g((E + 255) / 256, 4);
        fill_kernel<<<g, 256, 0, stream>>>(e_tt, e_aa, e_at, e_ta, rowptr, rank, col, E, N);
    }
    // 4. aggregation
    {
        dim3 g((N + 3) / 4, 4);
        agg_kernel<<<g, 256, 0, stream>>>(xb_tx, xb_ad, rowptr, cnt, col, aggb, N);
    }
    // 5. gemm0 + fused layer-1 transform
    {
        dim3 g((N + 63) / 64, 2);
        gemm0z_kernel<<<g, 256, 0, stream>>>(
            xb_tx, xb_ad, aggb,
            wb_tt, wb_at, wr0c_tx, wb_aa, wb_ta, wr0c_ad,
            b0c, wzb, b1c, z, outp, N);
    }
    // 6. layer-1 aggregation
    {
        dim3 g((N + 31) / 32, 2);
        l1_agg_kernel<<<g, 256, 0, stream>>>(rowptr, cnt, col, z, outp, N);
    }
}